// Round 8
// baseline (294.779 us; speedup 1.0000x reference)
//
#include <hip/hip_runtime.h>
#include <hip/hip_bf16.h>
#include <string.h>

typedef __attribute__((ext_vector_type(8))) short short8;
typedef __attribute__((ext_vector_type(4))) float floatx4;

// B=32, T=2048, D=512, U=512, M = B*T = 65536

__device__ inline uint packbf2(float lo, float hi) {
    __hip_bfloat162 h = __float22bfloat162_rn(make_float2(lo, hi));
    uint r; memcpy(&r, &h, 4); return r;
}

__device__ inline float tanh_fast(float x) {
    x = fminf(15.f, fmaxf(-15.f, x));
    float e = __expf(2.f * x);
    return __fdividef(e - 1.f, e + 1.f);
}

// async global->LDS, 16 B/lane; lds base wave-uniform (HW: lane i -> base+i*16)
__device__ inline void gload_lds16(const void* g, void* l) {
    __builtin_amdgcn_global_load_lds(
        (const __attribute__((address_space(1))) unsigned int*)g,
        (__attribute__((address_space(3))) unsigned int*)l, 16, 0, 0);
}

// ============================ NEW PATH (needs ~71 MB ws) ============================

// kprep2: bx<16384 -> cvt h_enc fp32 -> bf16 in A-frag chunk order
//   Ab chunk (G=row/16, kc=k/32) at (G*16+kc)*512; lane l=(row&15)+((k&31)>>3)*16, elem k&7
// bx 16384..16511 -> pack W1_enc into B-frag chunks Wp (kc,ng)
// bx 16512..16767 -> dec[b][u] = h_dec . W1_dec + b1
__global__ void kprep2(const float* __restrict__ h_enc, const float* __restrict__ W1,
                       const float* __restrict__ hdec, const float* __restrict__ b1,
                       ushort* __restrict__ Ab, ushort* __restrict__ Wp,
                       float* __restrict__ dec) {
    int bx = blockIdx.x;
    if (bx < 16384) {
        int slot = bx * 256 + threadIdx.x;        // 0..4194303
        int chunk = slot >> 6, l = slot & 63;
        int G = chunk >> 4, kc = chunk & 15;
        int m = l & 15, g = l >> 4;
        const float* src = h_enc + (size_t)(G * 16 + m) * 512 + kc * 32 + g * 8;
        floatx4 f0 = *(const floatx4*)src;
        floatx4 f1 = *(const floatx4*)(src + 4);
        uint4 u;
        u.x = packbf2(f0.x, f0.y); u.y = packbf2(f0.z, f0.w);
        u.z = packbf2(f1.x, f1.y); u.w = packbf2(f1.z, f1.w);
        *(uint4*)(Ab + (size_t)chunk * 512 + l * 8) = u;
    } else if (bx < 16512) {
        int wid = (bx - 16384) * 4 + (threadIdx.x >> 6);   // 0..511 chunks
        int l = threadIdx.x & 63;
        int kc = wid >> 5, ng = wid & 31;
        int m = l & 15, g = l >> 4;
        const float* src = W1 + (size_t)(kc * 32 + g * 8) * 512 + ng * 16 + m;
        uint u4[4];
        #pragma unroll
        for (int e = 0; e < 4; ++e)
            u4[e] = packbf2(src[(size_t)(2 * e) * 512], src[(size_t)(2 * e + 1) * 512]);
        *(uint4*)(Wp + (size_t)wid * 512 + l * 8) = *(uint4*)u4;
    } else {
        __shared__ float red[4][64];
        int blk = bx - 16512;
        int b = blk >> 3, ug = blk & 7;
        int tid = threadIdx.x;
        int u = ug * 64 + (tid & 63), dq = tid >> 6;
        const float* hb = hdec + b * 512 + dq * 128;
        const float* w = W1 + (size_t)(512 + dq * 128) * 512 + u;
        float a = 0.f;
        #pragma unroll 8
        for (int d = 0; d < 128; ++d)
            a += hb[d] * w[(size_t)d * 512];
        red[dq][tid & 63] = a;
        __syncthreads();
        if (tid < 64)
            dec[b * 512 + ug * 64 + tid] =
                red[0][tid] + red[1][tid] + red[2][tid] + red[3][tid] + b1[ug * 64 + tid];
    }
}

// kgemm3: 256 thr = 4 waves; tile 128 rows x 128 cols; K=512 in 16 phases.
// A: pre-swizzled bf16 via global_load_lds (double-buffered 2x8KB, 1 barrier/phase).
// B: reg ping-pong, one phase ahead. Wave (rh=w>>1, cg=w&1): 64x64, acc 4x4=64 AGPR.
// e2 col-partials (4 per row) -> e2p[colblk][65536]; summed in ksoftmax4.
__global__ __launch_bounds__(256, 3) void kgemm3(
        const ushort* __restrict__ Ab, const ushort* __restrict__ Wp,
        const float* __restrict__ dec, const float* __restrict__ W2,
        float* __restrict__ e2p) {
    __shared__ __align__(16) ushort As[2][4096];   // 2 x 8 KB: chunks i=0..7
    __shared__ float red[4][64];
    const int tid = threadIdx.x, lane = tid & 63, wave = tid >> 6;
    const int rh = wave >> 1, cg = wave & 1;
    const int rowblk = blockIdx.x >> 2, colblk = blockIdx.x & 3;
    const int r0 = rowblk * 128, G0 = rowblk * 8;
    const int bIdx = rowblk >> 4;                  // 16 rowblks per batch
    const int n0 = colblk * 128 + cg * 64;

    const ushort* wpb = Wp + (size_t)lane * 8;
    const int ngb = colblk * 8 + cg * 4;

    #define BLOADB(dst, kc) do { _Pragma("unroll")                              \
        for (int j = 0; j < 4; ++j)                                             \
            dst[j] = *(const short8*)(wpb + ((size_t)((kc) * 32 + ngb + j)) * 512); \
    } while (0)
    #define ASTAGE(buf, kc) do {                                                \
        gload_lds16(Ab + ((size_t)(G0 + wave * 2) * 16 + (kc)) * 512 + lane * 8,\
                    &As[buf][(wave * 2) * 512]);                                \
        gload_lds16(Ab + ((size_t)(G0 + wave * 2 + 1) * 16 + (kc)) * 512 + lane * 8,\
                    &As[buf][(wave * 2 + 1) * 512]);                            \
    } while (0)

    short8 bb[2][4];
    BLOADB(bb[0], 0);
    ASTAGE(0, 0);
    __syncthreads();                               // vmcnt(0) drain + barrier: buf0 ready

    floatx4 acc[4][4];
    #pragma unroll
    for (int i = 0; i < 4; i++)
        #pragma unroll
        for (int j = 0; j < 4; j++) acc[i][j] = (floatx4){0.f, 0.f, 0.f, 0.f};

    #pragma unroll
    for (int kc = 0; kc < 16; ++kc) {
        const int cur = kc & 1;
        if (kc < 15) {
            ASTAGE(cur ^ 1, kc + 1);               // async A for next phase
            BLOADB(bb[cur ^ 1], kc + 1);           // B regs for next phase
        }
        short8 afr[4];
        #pragma unroll
        for (int i = 0; i < 4; ++i)
            afr[i] = *(const short8*)&As[cur][(rh * 4 + i) * 512 + lane * 8];
        #pragma unroll
        for (int j = 0; j < 4; ++j)
            #pragma unroll
            for (int i = 0; i < 4; ++i)
                acc[i][j] = __builtin_amdgcn_mfma_f32_16x16x32_bf16(
                    afr[i], bb[cur][j], acc[i][j], 0, 0, 0);
        __syncthreads();                           // end-of-phase: drains this phase's issues
    }

    // epilogue: z += dec; p = sum_u tanh(z)*W2[u]; shfl(16) + cg-pair reduce
    const int c = lane & 15, g = lane >> 4;
    float w2v[4], dv[4];
    #pragma unroll
    for (int j = 0; j < 4; j++) {
        int n = n0 + j * 16 + c;
        w2v[j] = W2[n];
        dv[j]  = dec[bIdx * 512 + n];
    }
    #pragma unroll
    for (int i = 0; i < 4; i++) {
        #pragma unroll
        for (int r = 0; r < 4; r++) {
            float p = 0.f;
            #pragma unroll
            for (int j = 0; j < 4; j++)
                p += tanh_fast(acc[i][j][r] + dv[j]) * w2v[j];
            p += __shfl_xor(p, 1, 16);
            p += __shfl_xor(p, 2, 16);
            p += __shfl_xor(p, 4, 16);
            p += __shfl_xor(p, 8, 16);
            if (c == 0) red[wave][i * 16 + g * 4 + r] = p;
        }
    }
    __syncthreads();
    if (tid < 128) {
        int half = tid >> 6, rr = tid & 63;
        e2p[(size_t)colblk * 65536 + r0 + half * 64 + rr] =
            red[half * 2][rr] + red[half * 2 + 1][rr];
    }
    #undef BLOADB
    #undef ASTAGE
}

// ksoftmax4: sum 4 col-partials, relu(+b2), softmax over T -> attn
__global__ void ksoftmax4(const float* __restrict__ e2p, const float* __restrict__ b2,
                          float* __restrict__ attn) {
    int b = blockIdx.x, tid = threadIdx.x;
    int lane = tid & 63, wave = tid >> 6;
    float b2v = b2[0];
    float f[8];
    float m = -1e30f;
    #pragma unroll
    for (int i = 0; i < 8; i++) {
        int idx = b * 2048 + i * 256 + tid;
        float z = e2p[idx] + e2p[65536 + idx] + e2p[131072 + idx] + e2p[196608 + idx] + b2v;
        f[i] = fmaxf(z, 0.f);
        m = fmaxf(m, f[i]);
    }
    #pragma unroll
    for (int off = 1; off < 64; off <<= 1) m = fmaxf(m, __shfl_xor(m, off));
    __shared__ float red[4], red2[4];
    if (lane == 0) red[wave] = m;
    __syncthreads();
    m = fmaxf(fmaxf(red[0], red[1]), fmaxf(red[2], red[3]));
    float s = 0.f;
    #pragma unroll
    for (int i = 0; i < 8; i++) { f[i] = __expf(f[i] - m); s += f[i]; }
    #pragma unroll
    for (int off = 1; off < 64; off <<= 1) s += __shfl_xor(s, off);
    if (lane == 0) red2[wave] = s;
    __syncthreads();
    s = red2[0] + red2[1] + red2[2] + red2[3];
    float inv = 1.f / s;
    #pragma unroll
    for (int i = 0; i < 8; i++)
        attn[b * 2048 + i * 256 + tid] = f[i] * inv;
}

// ============================ FALLBACK PATH (r7, ~2.9 MB ws) ============================

__global__ void kprep(const float* __restrict__ W1, const float* __restrict__ hdec,
                      const float* __restrict__ b1, ushort* __restrict__ Wp,
                      float* __restrict__ dec) {
    if (blockIdx.x < 128) {
        int wid = blockIdx.x * 4 + (threadIdx.x >> 6);
        int l = threadIdx.x & 63;
        int kc = wid >> 5, ng = wid & 31;
        int m = l & 15, g = l >> 4;
        const float* src = W1 + (size_t)(kc * 32 + g * 8) * 512 + ng * 16 + m;
        uint u4[4];
        #pragma unroll
        for (int e = 0; e < 4; ++e)
            u4[e] = packbf2(src[(size_t)(2 * e) * 512], src[(size_t)(2 * e + 1) * 512]);
        *(uint4*)(Wp + (size_t)wid * 512 + l * 8) = *(uint4*)u4;
    } else {
        __shared__ float red[4][64];
        int blk = blockIdx.x - 128;
        int b = blk >> 3, ug = blk & 7;
        int tid = threadIdx.x;
        int u = ug * 64 + (tid & 63), dq = tid >> 6;
        const float* hb = hdec + b * 512 + dq * 128;
        const float* w = W1 + (size_t)(512 + dq * 128) * 512 + u;
        float a = 0.f;
        #pragma unroll 8
        for (int d = 0; d < 128; ++d)
            a += hb[d] * w[(size_t)d * 512];
        red[dq][tid & 63] = a;
        __syncthreads();
        if (tid < 64)
            dec[b * 512 + ug * 64 + tid] =
                red[0][tid] + red[1][tid] + red[2][tid] + red[3][tid] + b1[ug * 64 + tid];
    }
}

__global__ __launch_bounds__(256, 2) void kgemm_fb(
        const float* __restrict__ A, const ushort* __restrict__ Wp,
        const float* __restrict__ dec, const float* __restrict__ W2,
        float* __restrict__ e2) {
    __shared__ __align__(16) ushort As[32768];
    __shared__ float red[4][64];
    const int tid = threadIdx.x;
    const int lane = tid & 63, wave = tid >> 6;
    const int r0 = blockIdx.x * 64;
    const int bIdx = blockIdx.x >> 5;

    const ushort* wp = Wp + (size_t)lane * 8 + (size_t)(wave * 8) * 512;
    #define BLOADF(dst, kc) do { _Pragma("unroll")                         \
        for (int j = 0; j < 8; ++j)                                        \
            dst[j] = *(const short8*)(wp + ((size_t)(kc) * 32 + j) * 512); \
    } while (0)

    short8 bA[8], bB[8];
    BLOADF(bA, 0);
    {
        const int m = lane & 15, g = lane >> 4;
        #pragma unroll
        for (int cc = 0; cc < 16; ++cc) {
            int chunk = wave * 16 + cc;
            int kc = chunk >> 2, i = chunk & 3;
            const float* gp = A + (size_t)(r0 + i * 16 + m) * 512 + kc * 32 + g * 8;
            floatx4 f0 = *(const floatx4*)gp;
            floatx4 f1 = *(const floatx4*)(gp + 4);
            uint4 u;
            u.x = packbf2(f0.x, f0.y); u.y = packbf2(f0.z, f0.w);
            u.z = packbf2(f1.x, f1.y); u.w = packbf2(f1.z, f1.w);
            *(uint4*)&As[chunk * 512 + lane * 8] = u;
        }
    }
    __syncthreads();

    floatx4 acc[4][8];
    #pragma unroll
    for (int i = 0; i < 4; i++)
        #pragma unroll
        for (int j = 0; j < 8; j++) acc[i][j] = (floatx4){0.f, 0.f, 0.f, 0.f};

    #define COMPUTEF(kc, bfr) do {                                            \
        short8 afr[4];                                                        \
        _Pragma("unroll")                                                     \
        for (int i = 0; i < 4; ++i)                                           \
            afr[i] = *(const short8*)&As[((kc) * 4 + i) * 512 + lane * 8];    \
        _Pragma("unroll")                                                     \
        for (int i = 0; i < 4; ++i)                                           \
            _Pragma("unroll")                                                 \
            for (int j = 0; j < 8; ++j)                                       \
                acc[i][j] = __builtin_amdgcn_mfma_f32_16x16x32_bf16(          \
                    afr[i], bfr[j], acc[i][j], 0, 0, 0);                      \
    } while (0)

    #pragma unroll
    for (int kc = 0; kc < 16; kc += 2) {
        BLOADF(bB, kc + 1);
        COMPUTEF(kc, bA);
        if (kc < 14) BLOADF(bA, kc + 2);
        COMPUTEF(kc + 1, bB);
    }

    const int c = lane & 15, g = lane >> 4;
    float w2v[8], dv[8];
    #pragma unroll
    for (int j = 0; j < 8; j++) {
        int n = wave * 128 + j * 16 + c;
        w2v[j] = W2[n];
        dv[j]  = dec[bIdx * 512 + n];
    }
    #pragma unroll
    for (int i = 0; i < 4; i++) {
        #pragma unroll
        for (int r = 0; r < 4; r++) {
            float p = 0.f;
            #pragma unroll
            for (int j = 0; j < 8; j++)
                p += tanh_fast(acc[i][j][r] + dv[j]) * w2v[j];
            p += __shfl_xor(p, 1, 16);
            p += __shfl_xor(p, 2, 16);
            p += __shfl_xor(p, 4, 16);
            p += __shfl_xor(p, 8, 16);
            if (c == 0) red[wave][i * 16 + g * 4 + r] = p;
        }
    }
    __syncthreads();
    if (tid < 64)
        e2[r0 + tid] = red[0][tid] + red[1][tid] + red[2][tid] + red[3][tid];
    #undef BLOADF
    #undef COMPUTEF
}

__global__ void ksoftmax1(const float* __restrict__ e2, const float* __restrict__ b2,
                          float* __restrict__ attn) {
    int b = blockIdx.x, tid = threadIdx.x;
    int lane = tid & 63, wave = tid >> 6;
    float b2v = b2[0];
    float f[8];
    float m = -1e30f;
    #pragma unroll
    for (int i = 0; i < 8; i++) {
        float z = e2[b * 2048 + i * 256 + tid] + b2v;
        f[i] = fmaxf(z, 0.f);
        m = fmaxf(m, f[i]);
    }
    #pragma unroll
    for (int off = 1; off < 64; off <<= 1) m = fmaxf(m, __shfl_xor(m, off));
    __shared__ float red[4], red2[4];
    if (lane == 0) red[wave] = m;
    __syncthreads();
    m = fmaxf(fmaxf(red[0], red[1]), fmaxf(red[2], red[3]));
    float s = 0.f;
    #pragma unroll
    for (int i = 0; i < 8; i++) { f[i] = __expf(f[i] - m); s += f[i]; }
    #pragma unroll
    for (int off = 1; off < 64; off <<= 1) s += __shfl_xor(s, off);
    if (lane == 0) red2[wave] = s;
    __syncthreads();
    s = red2[0] + red2[1] + red2[2] + red2[3];
    float inv = 1.f / s;
    #pragma unroll
    for (int i = 0; i < 8; i++)
        attn[b * 2048 + i * 256 + tid] = f[i] * inv;
}

// ============================ SHARED TAIL ============================

__global__ void kctx(const float* __restrict__ A, const float* __restrict__ attn,
                     float* __restrict__ part) {
    __shared__ float at[64];
    __shared__ float4 red[128];
    int b = blockIdx.x, ch = blockIdx.y, tid = threadIdx.x;
    if (tid < 64) at[tid] = attn[b * 2048 + ch * 64 + tid];
    __syncthreads();
    int dt = tid & 127, th = tid >> 7;
    const float* base = A + ((size_t)b * 2048 + ch * 64 + th * 32) * 512 + dt * 4;
    const float* aw = at + th * 32;
    float4 acc = (float4){0.f, 0.f, 0.f, 0.f};
    #pragma unroll 8
    for (int tt = 0; tt < 32; ++tt) {
        float a = aw[tt];
        float4 h = *(const float4*)(base + (size_t)tt * 512);
        acc.x += a * h.x; acc.y += a * h.y; acc.z += a * h.z; acc.w += a * h.w;
    }
    if (th == 1) red[dt] = acc;
    __syncthreads();
    if (th == 0) {
        float4 o = red[dt];
        float4 r; r.x = acc.x + o.x; r.y = acc.y + o.y;
        r.z = acc.z + o.z; r.w = acc.w + o.w;
        *(float4*)(part + ((size_t)b * 32 + ch) * 512 + dt * 4) = r;
    }
}

__global__ void kfin(const float* __restrict__ part, float* __restrict__ ctx) {
    int idx = blockIdx.x * 256 + threadIdx.x;
    int b = idx >> 9, d = idx & 511;
    const float* p = part + (size_t)b * 32 * 512 + d;
    float s = 0.f;
    #pragma unroll
    for (int cI = 0; cI < 32; ++cI) s += p[cI * 512];
    ctx[idx] = s;
}

extern "C" void kernel_launch(void* const* d_in, const int* in_sizes, int n_in,
                              void* d_out, int out_size, void* d_ws, size_t ws_size,
                              hipStream_t stream) {
    const float* h_enc = (const float*)d_in[0];
    const float* h_dec = (const float*)d_in[1];
    const float* W1    = (const float*)d_in[2];
    const float* b1    = (const float*)d_in[3];
    const float* W2    = (const float*)d_in[4];
    const float* b2    = (const float*)d_in[5];
    float* out  = (float*)d_out;
    float* ctx  = out;              // 32*512
    float* attn = out + 32 * 512;   // 32*2048

    char* ws = (char*)d_ws;
    const size_t AB_SZ  = (size_t)65536 * 512 * 2;   // 64 MB
    const size_t WP_SZ  = (size_t)512 * 512 * 2;     // 512 KB
    const size_t DEC_SZ = (size_t)32 * 512 * 4;      // 64 KB
    const size_t E2P_SZ = (size_t)4 * 65536 * 4;     // 1 MB
    const size_t PART_SZ = (size_t)32 * 32 * 512 * 4; // 2 MB

    if (ws_size >= AB_SZ + WP_SZ + DEC_SZ + E2P_SZ + PART_SZ) {
        ushort* Ab  = (ushort*)ws;
        ushort* Wp  = (ushort*)(ws + AB_SZ);
        float*  dec = (float*)(ws + AB_SZ + WP_SZ);
        float*  e2p = (float*)(ws + AB_SZ + WP_SZ + DEC_SZ);
        float*  part = (float*)(ws + AB_SZ + WP_SZ + DEC_SZ + E2P_SZ);

        kprep2<<<16768, 256, 0, stream>>>(h_enc, W1, h_dec, b1, Ab, Wp, dec);
        kgemm3<<<2048, 256, 0, stream>>>(Ab, Wp, dec, W2, e2p);
        ksoftmax4<<<32, 256, 0, stream>>>(e2p, b2, attn);
        dim3 g3(32, 32);
        kctx<<<g3, 256, 0, stream>>>(h_enc, attn, part);
        kfin<<<64, 256, 0, stream>>>(part, ctx);
    } else {
        ushort* Wp  = (ushort*)ws;
        float*  dec = (float*)(ws + WP_SZ);
        float*  e2  = (float*)(ws + WP_SZ + DEC_SZ);
        float*  part = (float*)(ws + WP_SZ + DEC_SZ + (size_t)65536 * 4);

        kprep<<<384, 256, 0, stream>>>(W1, h_dec, b1, Wp, dec);
        kgemm_fb<<<1024, 256, 0, stream>>>(h_enc, Wp, dec, W2, e2);
        ksoftmax1<<<32, 256, 0, stream>>>(e2, b2, attn);
        dim3 g3(32, 32);
        kctx<<<g3, 256, 0, stream>>>(h_enc, attn, part);
        kfin<<<64, 256, 0, stream>>>(part, ctx);
    }
}